// Round 4
// baseline (305.831 us; speedup 1.0000x reference)
//
#include <hip/hip_runtime.h>
#include <math.h>

// Bahdanau attention, B=32, T=2048, D=512, U=512, fp32 in/out.
// Round 11: counted-vmcnt software pipeline in score_fused (T3/T4). r10's
// per-step __syncthreads drained vmcnt(0) ~400cy after DMA issue (HBM lat
// ~900cy) with 1 block/CU -> ~7.2k cy/step. Now: A prefetch depth 2 (4 LDS
// bufs), B depth 1 (2 bufs); per step issue B(t+1),A(t+2), wait vmcnt(8)
// (never 0 in-loop), raw s_barrier pair, 32 MFMA. Also B LDS slot swizzle
// lq^((r>>1)&3) (was lq^(r&3), a 4-way conflict) -> uniform 2-way (free).

#define B_ 32
#define T_ 2048
#define D_ 512
#define U_ 512
#define M_ (B_ * T_)

typedef _Float16 half8 __attribute__((ext_vector_type(8)));
typedef float floatx4 __attribute__((ext_vector_type(4)));

__device__ __forceinline__ float fast_tanh(float x) {
  x = fminf(fmaxf(x, -20.f), 20.f);
  const float e = __expf(2.f * x);
  return 1.f - 2.f / (e + 1.f);
}

__device__ __forceinline__ void load_lds16f(const float* g, float* l) {
  __builtin_amdgcn_global_load_lds(
      (const __attribute__((address_space(1))) void*)g,
      (__attribute__((address_space(3))) void*)l, 16, 0, 0);
}

__device__ __forceinline__ void load_lds16h(const _Float16* g, _Float16* l) {
  __builtin_amdgcn_global_load_lds(
      (const __attribute__((address_space(1))) void*)g,
      (__attribute__((address_space(3))) void*)l, 16, 0, 0);
}

// ---------------- prep: W1->w1t | projq | zero context ---------------------
__global__ __launch_bounds__(256) void prep_fused(
    const float* __restrict__ W1, const float* __restrict__ query,
    const float* __restrict__ W2, const float* __restrict__ b2,
    _Float16* __restrict__ w1t, float* __restrict__ projq,
    float* __restrict__ context) {
  __shared__ float sh[64 * 65];
  const int bx = blockIdx.x;
  const int tid = threadIdx.x;
  if (bx < 64) {
    const int t = bx;
    const int k0 = (t >> 3) * 64, u0 = (t & 7) * 64;
    float(*sm)[65] = (float(*)[65])sh;
    const int lu = tid & 63;
    const int g = tid >> 6;
#pragma unroll
    for (int i = 0; i < 16; ++i) {
      const int row = g * 16 + i;
      sm[row][lu] = W1[(long)(k0 + row) * U_ + u0 + lu];
    }
    __syncthreads();
#pragma unroll
    for (int i = 0; i < 16; ++i) {
      const int row = g * 16 + i;
      w1t[(long)(u0 + row) * D_ + k0 + lu] = (_Float16)sm[lu][row];
    }
  } else {
    const int t = bx - 64;  // [0,64)
    const int gid = t * 256 + tid;
    context[gid] = 0.f;  // 16384 floats
    const int b = t >> 1;
    const int u = (t & 1) * 256 + tid;
    for (int d = tid; d < D_; d += 256) sh[d] = query[b * D_ + d];
    __syncthreads();
    float acc = 0.f;
#pragma unroll 8
    for (int d = 0; d < D_; ++d) acc += sh[d] * W2[d * U_ + u];
    projq[b * U_ + u] = acc + b2[u];
  }
}

// ---------------- scores: fused fp32-read MFMA, 128m x 512u per block ------
// Grid M/128 = 512 blocks, 512 threads = 8 waves (2m x 4u).
// Wave = 64m x 128u via 4x8 grid of 16x16x32 MFMA (acc 128 regs).
// A: values fp32 -> LDS [4 bufs][128][32] via global_load_lds, prefetch
//    depth 2, source-side XOR swizzle slot = chunk^(r&7) (2-way, free).
// B: w1t f16 -> LDS [2 bufs][512][32], depth 1, slot = chunk^((r>>1)&3)
//    (uniform 2-way). Steady loop: issue B(t+1), A(t+2), s_waitcnt vmcnt(8)
//    [never 0], s_barrier, frag ds_reads + cvt, lgkmcnt(0)+sched_barrier,
//    s_barrier, 32 MFMA. Tail peeled with vmcnt(6)/vmcnt(0).
// Frag layouts (verified r2-r6): A[m=lane&15][k=(lane>>4)*8+j],
// B[k=(lane>>4)*8+j][n=lane&15], C[row=(lane>>4)*4+reg][col=lane&15].
__global__ __launch_bounds__(512, 1) void score_fused(
    const float* __restrict__ values, const _Float16* __restrict__ w1t,
    const float* __restrict__ b1, const float* __restrict__ projq,
    const float* __restrict__ V, float* __restrict__ scores) {
  const int m0 = blockIdx.x * 128;
  const int b = blockIdx.x >> 4;  // 2048/128 = 16 row-blocks per batch
  const int tid = threadIdx.x;
  const int lane = tid & 63;
  const int w = tid >> 6;          // 0..7
  const int wm = (w & 1) * 64;     // m-half
  const int wu = (w >> 1) * 128;   // u-quarter
  const int ln = lane & 15;
  const int lq = lane >> 4;

  __shared__ alignas(16) float As[4][128 * 32];     // 64 KB, depth-2 A
  __shared__ alignas(16) _Float16 Bs[2][512 * 32];  // 64 KB, depth-1 B
  __shared__ float red[4][128];                     // 2 KB

  // A-DMA: wave w stages rows [16w,16w+16) per step, 2 instrs of 8 rows.
  // lane l -> row +(l>>3), slot l&7; source chunk (l&7)^(l>>3).
  const int dr = lane >> 3;
  const int dc = (lane & 7) ^ dr;
  const float* gA[2];
#pragma unroll
  for (int j = 0; j < 2; ++j) {
    const int r = w * 16 + j * 8 + dr;
    gA[j] = values + (long)(m0 + r) * D_ + dc * 4;
  }

  // B-DMA: wave w stages rows [64w,64w+64) per step, 4 instrs of 16 rows.
  // lane l -> row +(l>>2), slot l&3; source chunk (l&3)^((l>>3)&3)
  // [row bits 1..2 within 16-row group = (l>>3)&3].
  const int br = lane >> 2;
  const int bc = (lane & 3) ^ ((lane >> 3) & 3);
  const _Float16* gB[4];
#pragma unroll
  for (int i = 0; i < 4; ++i) {
    const int r = w * 64 + i * 16 + br;
    gB[i] = w1t + (long)r * D_ + bc * 8;
  }

  floatx4 acc[4][8] = {};

  auto issueA = [&](int T) {
    float* dst = &As[T & 3][(w * 16) * 32];
    const long off = (long)T * 32;
#pragma unroll
    for (int j = 0; j < 2; ++j)
      load_lds16f(gA[j] + off, dst + j * 8 * 32);
  };
  auto issueB = [&](int T) {
    _Float16* dst = &Bs[T & 1][(w * 64) * 32];
    const long off = (long)T * 32;
#pragma unroll
    for (int i = 0; i < 4; ++i)
      load_lds16h(gB[i] + off, dst + i * 16 * 32);
  };
  auto consume = [&](int t) {
    asm volatile("s_barrier" ::: "memory");  // all waves' step-t data landed
    const _Float16* Bp = Bs[t & 1];
    const float* Ap = As[t & 3];
    half8 bf[8];
#pragma unroll
    for (int ni = 0; ni < 8; ++ni) {
      const int r = wu + ni * 16 + ln;
      bf[ni] = *(const half8*)&Bp[r * 32 + ((lq ^ ((r >> 1) & 3)) * 8)];
    }
    half8 af[4];
#pragma unroll
    for (int mi = 0; mi < 4; ++mi) {
      const int r = wm + mi * 16 + ln;
      const float* row = &Ap[r * 32];
      const float4 lo = *(const float4*)(row + (((2 * lq) ^ (r & 7)) * 4));
      const float4 hi = *(const float4*)(row + (((2 * lq + 1) ^ (r & 7)) * 4));
      af[mi] = half8{(_Float16)lo.x, (_Float16)lo.y, (_Float16)lo.z,
                     (_Float16)lo.w, (_Float16)hi.x, (_Float16)hi.y,
                     (_Float16)hi.z, (_Float16)hi.w};
    }
    asm volatile("s_waitcnt lgkmcnt(0)" ::: "memory");
    __builtin_amdgcn_sched_barrier(0);
    asm volatile("s_barrier" ::: "memory");  // frags in regs; bufs freeable
#pragma unroll
    for (int mi = 0; mi < 4; ++mi)
#pragma unroll
      for (int ni = 0; ni < 8; ++ni)
        acc[mi][ni] = __builtin_amdgcn_mfma_f32_16x16x32_f16(
            af[mi], bf[ni], acc[mi][ni], 0, 0, 0);
  };

  // prologue: A(0), B(0), A(1) in flight
  issueA(0);
  issueB(0);
  issueA(1);

  // steady state: queue at wait = {A(t),B(t),A(t+1),B(t+1),A(t+2)} = 14;
  // vmcnt(8) completes exactly A(t)+B(t).
  for (int t = 0; t < 14; ++t) {
    issueB(t + 1);
    issueA(t + 2);
    asm volatile("s_waitcnt vmcnt(8)" ::: "memory");
    consume(t);
  }
  issueB(15);
  asm volatile("s_waitcnt vmcnt(6)" ::: "memory");
  consume(14);
  asm volatile("s_waitcnt vmcnt(0)" ::: "memory");
  consume(15);

  // Epilogue: full row scores (each block owns its 128 rows exclusively).
  float pre[8], vv[8];
#pragma unroll
  for (int ni = 0; ni < 8; ++ni) {
    const int u = wu + ni * 16 + ln;
    pre[ni] = b1[u] + projq[b * U_ + u];
    vv[ni] = V[u];
  }
#pragma unroll
  for (int mi = 0; mi < 4; ++mi) {
#pragma unroll
    for (int r = 0; r < 4; ++r) {
      float t = 0.f;
#pragma unroll
      for (int ni = 0; ni < 8; ++ni)
        t += fast_tanh(acc[mi][ni][r] + pre[ni]) * vv[ni];
      t += __shfl_xor(t, 1);
      t += __shfl_xor(t, 2);
      t += __shfl_xor(t, 4);
      t += __shfl_xor(t, 8);
      if (ln == 0) red[w >> 1][wm + mi * 16 + lq * 4 + r] = t;
    }
  }
  __syncthreads();
  if (tid < 128)
    scores[m0 + tid] =
        red[0][tid] + red[1][tid] + red[2][tid] + red[3][tid];
}

// ---------------- fused softmax + context ----------------
__global__ __launch_bounds__(256) void softmax_context_kernel(
    const float* __restrict__ scores, const float* __restrict__ values,
    float* __restrict__ weights, float* __restrict__ context) {
  const int b = blockIdx.x;
  const int t0 = blockIdx.y * 64;
  const int tid = threadIdx.x;

  // full-batch softmax stats
  float v[8];
  float mx = -INFINITY;
#pragma unroll
  for (int i = 0; i < 8; ++i) {
    v[i] = scores[b * T_ + i * 256 + tid];
    mx = fmaxf(mx, v[i]);
  }
#pragma unroll
  for (int off = 32; off > 0; off >>= 1) mx = fmaxf(mx, __shfl_down(mx, off));
  __shared__ float sm[4], ss[4];
  if ((tid & 63) == 0) sm[tid >> 6] = mx;
  __syncthreads();
  mx = fmaxf(fmaxf(sm[0], sm[1]), fmaxf(sm[2], sm[3]));
  float sum = 0.f;
#pragma unroll
  for (int i = 0; i < 8; ++i) sum += __expf(v[i] - mx);
#pragma unroll
  for (int off = 32; off > 0; off >>= 1) sum += __shfl_down(sum, off);
  if ((tid & 63) == 0) ss[tid >> 6] = sum;
  __syncthreads();
  const float inv = 1.f / (ss[0] + ss[1] + ss[2] + ss[3]);

  // weights for our 64 rows
  __shared__ float wsh[64];
  if (tid < 64) {
    const float ww = __expf(scores[b * T_ + t0 + tid] - mx) * inv;
    wsh[tid] = ww;
    weights[b * T_ + t0 + tid] = ww;
  }
  __syncthreads();

  // context partial
  const int g = tid >> 7;
  const int dx = tid & 127;
  __shared__ float4 part[128];
  float4 acc = make_float4(0.f, 0.f, 0.f, 0.f);
  const float4* vp = (const float4*)(values + (long)(b * T_ + t0 + g) * D_) + dx;
#pragma unroll 4
  for (int t = 0; t < 32; ++t) {
    const float4 x = vp[(long)(2 * t) * (D_ / 4)];
    const float ww = wsh[2 * t + g];
    acc.x += ww * x.x; acc.y += ww * x.y; acc.z += ww * x.z; acc.w += ww * x.w;
  }
  if (g == 0) part[dx] = acc;
  __syncthreads();
  if (g == 1) {
    const float4 p = part[dx];
    atomicAdd(&context[b * D_ + dx * 4 + 0], acc.x + p.x);
    atomicAdd(&context[b * D_ + dx * 4 + 1], acc.y + p.y);
    atomicAdd(&context[b * D_ + dx * 4 + 2], acc.z + p.z);
    atomicAdd(&context[b * D_ + dx * 4 + 3], acc.w + p.w);
  }
}

extern "C" void kernel_launch(void* const* d_in, const int* in_sizes, int n_in,
                              void* d_out, int out_size, void* d_ws, size_t ws_size,
                              hipStream_t stream) {
  const float* values = (const float*)d_in[0];
  const float* query = (const float*)d_in[1];
  const float* W1 = (const float*)d_in[2];
  const float* b1 = (const float*)d_in[3];
  const float* W2 = (const float*)d_in[4];
  const float* b2 = (const float*)d_in[5];
  const float* V = (const float*)d_in[6];
  // d_in[7] = bV: unused — softmax is shift-invariant.

  float* out = (float*)d_out;
  float* context = out;            // [32,512]
  float* weights = out + B_ * D_;  // [32,2048]
  float* projq = (float*)d_ws;                                // 64KB
  float* scores = projq + B_ * U_;                            // 256KB
  _Float16* w1t = (_Float16*)((char*)d_ws + 65536 + 262144);  // 512KB

  prep_fused<<<128, 256, 0, stream>>>(W1, query, W2, b2, w1t, projq, context);
  score_fused<<<M_ / 128, 512, 0, stream>>>(values, w1t, b1, projq, V, scores);
  softmax_context_kernel<<<dim3(B_, T_ / 64), 256, 0, stream>>>(
      scores, values, weights, context);
}